// Round 1
// 267.147 us; speedup vs baseline: 1.0349x; 1.0349x over previous
//
#include <hip/hip_runtime.h>

// SIZE = (D,H,W) = (160,192,160), B=2, C=2.
#define DD 160
#define HH 192
#define WW 160
#define SP (DD * HH * WW)
#define NB 2
#define NC 2

// Tile per block and staged (edge-replicated) region.
// 512 threads/block, 4 samples/thread.
#define TX 32
#define TY 8
#define TZ 8
#define RXW 40                 // x: [X0-4, X0+35]  supports dx in [-4,4)
#define RYH 15                 // y: [Y0-3, Y0+11]  supports dy in [-3,4)
#define RZD 15                 // z: [Z0-3, Z0+11]  supports dz in [-3,4)
#define REGC (RZD * RYH * RXW) // 9000 voxels; LDS = 2ch*4B*9000 = 72.0 KB -> 2 blocks/CU
#define NCHUNK (REGC / 4)      // 2250 4-voxel chunks
#define NITER 5                // ceil(2250/512)

#define NTX 5
#define NTY 24
#define NTZ 20
#define NTILES (NTX * NTY * NTZ * NB)   // 4800 blocks
#define PER_XCD (NTILES / 8)

typedef float v2f __attribute__((ext_vector_type(2)));
typedef float v4f __attribute__((ext_vector_type(4)));

__device__ __forceinline__ v4f ld4_nt(const float* p) {
    return __builtin_nontemporal_load(reinterpret_cast<const v4f*>(p));
}
__device__ __forceinline__ void st4_nt(float* p, v4f v) {
    __builtin_nontemporal_store(v, reinterpret_cast<v4f*>(p));
}
__device__ __forceinline__ v2f ld2g(const float* p) {
    return *reinterpret_cast<const v2f*>(p);
}
__device__ __forceinline__ v2f s2(float f) { v2f v = {f, f}; return v; }

// Rare fallback: displacement outside staged halo — full global trilinear.
__device__ __forceinline__ void sample_global(
    const float* __restrict__ s0, const float* __restrict__ s1,
    int x, int y, int z, float dx, float dy, float dz,
    float& a0, float& a1)
{
    float sx = (float)x + dx, sy = (float)y + dy, sz = (float)z + dz;
    float xf = floorf(sx), yf = floorf(sy), zf = floorf(sz);
    float fx = sx - xf, fy = sy - yf, fz = sz - zf;
    int x0 = (int)xf, y0 = (int)yf, z0 = (int)zf;
    int x1 = x0 + 1, y1 = y0 + 1, z1 = z0 + 1;

    float wx0 = (x0 >= 0 && x0 < WW) ? (1.0f - fx) : 0.0f;
    float wx1 = (x1 >= 0 && x1 < WW) ? fx : 0.0f;
    float wy0 = (y0 >= 0 && y0 < HH) ? (1.0f - fy) : 0.0f;
    float wy1 = (y1 >= 0 && y1 < HH) ? fy : 0.0f;
    float wz0 = (z0 >= 0 && z0 < DD) ? (1.0f - fz) : 0.0f;
    float wz1 = (z1 >= 0 && z1 < DD) ? fz : 0.0f;

    int p  = min(max(x0, 0), WW - 2);
    int i0 = min(max(x0, 0), WW - 1) - p;
    int i1 = min(max(x1, 0), WW - 1) - p;
    int cy0 = min(max(y0, 0), HH - 1), cy1 = min(max(y1, 0), HH - 1);
    int cz0 = min(max(z0, 0), DD - 1), cz1 = min(max(z1, 0), DD - 1);

    int o00 = (cz0 * HH + cy0) * WW + p;
    int o01 = (cz0 * HH + cy1) * WW + p;
    int o10 = (cz1 * HH + cy0) * WW + p;
    int o11 = (cz1 * HH + cy1) * WW + p;

    float w00 = wz0 * wy0, w01 = wz0 * wy1, w10 = wz1 * wy0, w11 = wz1 * wy1;

    v2f c0_00 = ld2g(s0 + o00); v2f c1_00 = ld2g(s1 + o00);
    v2f c0_01 = ld2g(s0 + o01); v2f c1_01 = ld2g(s1 + o01);
    v2f c0_10 = ld2g(s0 + o10); v2f c1_10 = ld2g(s1 + o10);
    v2f c0_11 = ld2g(s0 + o11); v2f c1_11 = ld2g(s1 + o11);

    #define PICK(v, i) ((i) ? (v).y : (v).x)
    float r0, r1;
    r0  = w00 * (wx0 * PICK(c0_00, i0) + wx1 * PICK(c0_00, i1));
    r1  = w00 * (wx0 * PICK(c1_00, i0) + wx1 * PICK(c1_00, i1));
    r0 += w01 * (wx0 * PICK(c0_01, i0) + wx1 * PICK(c0_01, i1));
    r1 += w01 * (wx0 * PICK(c1_01, i0) + wx1 * PICK(c1_01, i1));
    r0 += w10 * (wx0 * PICK(c0_10, i0) + wx1 * PICK(c0_10, i1));
    r1 += w10 * (wx0 * PICK(c1_10, i0) + wx1 * PICK(c1_10, i1));
    r0 += w11 * (wx0 * PICK(c0_11, i0) + wx1 * PICK(c0_11, i1));
    r1 += w11 * (wx0 * PICK(c1_11, i0) + wx1 * PICK(c1_11, i1));
    #undef PICK
    a0 = r0; a1 = r1;
}

__global__ __launch_bounds__(512, 4) void st_warp_kernel(
    const float* __restrict__ src,   // [B, C, D, H, W]
    const float* __restrict__ flow,  // [B, 3, D, H, W]
    float* __restrict__ out)         // [B, C, D, H, W]
{
    // Channel-interleaved staged region: sbuf[2*v] = c0, sbuf[2*v+1] = c1.
    __shared__ float sbuf[2 * REGC];   // 72,000 B -> 2 blocks/CU (16 waves)

    int u   = blockIdx.x;
    int tl  = (u & 7) * PER_XCD + (u >> 3);   // XCD-contiguous tile ranges
    int tx  = tl % NTX;  int t2 = tl / NTX;
    int ty  = t2 % NTY;  int t3 = t2 / NTY;
    int tz  = t3 % NTZ;  int b  = t3 / NTZ;
    int X0 = tx * TX, Y0 = ty * TY, Z0 = tz * TZ;
    int tid = threadIdx.x;

    const float* sb = src + b * NC * SP;   // channel 0 base (c1 at +SP)

    // ---- Stage region: issue all global loads first (deep MLP) ----
    v4f va[NITER], vb[NITER];
    int  ad[NITER];
    #pragma unroll
    for (int i = 0; i < NITER; ++i) {
        int c = tid + i * 512;
        if (i < NITER - 1 || c < NCHUNK) {
            int lz  = c / 150;  int r2 = c - lz * 150;   // 150 = RYH*RXW/4
            int ly  = r2 / 10;  int lxc = r2 - ly * 10;  // 10 = RXW/4
            int mz = min(max(Z0 - 3 + lz, 0), DD - 1);
            int my = min(max(Y0 - 3 + ly, 0), HH - 1);
            int mx = X0 - 4 + lxc * 4;
            const float* p = sb + (mz * HH + my) * WW;
            v4f A, B;
            if (mx >= 0 && mx <= WW - 4) {
                A = *reinterpret_cast<const v4f*>(p + mx);
                B = *reinterpret_cast<const v4f*>(p + SP + mx);
            } else {   // volume x-edge chunks only
                int m0 = min(max(mx,     0), WW - 1);
                int m1 = min(max(mx + 1, 0), WW - 1);
                int m2 = min(max(mx + 2, 0), WW - 1);
                int m3 = min(max(mx + 3, 0), WW - 1);
                A.x = p[m0]; A.y = p[m1]; A.z = p[m2]; A.w = p[m3];
                B.x = p[SP + m0]; B.y = p[SP + m1]; B.z = p[SP + m2]; B.w = p[SP + m3];
            }
            va[i] = A; vb[i] = B;
            ad[i] = 2 * ((lz * RYH + ly) * RXW + lxc * 4);  // 32B-aligned
        } else {
            ad[i] = -1;
        }
    }

    // ---- Flow loads (in flight across the barrier) ----
    int rr = tid >> 3;
    int xi = (tid & 7) << 2;
    int yl = rr & 7, zl = rr >> 3;
    int y = Y0 + yl, z = Z0 + zl, x = X0 + xi;
    int fo = b * 3 * SP + (z * HH + y) * WW + x;
    v4f dxv = ld4_nt(flow + fo);
    v4f dyv = ld4_nt(flow + fo + SP);
    v4f dzv = ld4_nt(flow + fo + 2 * SP);

    // ---- Interleave channels, write LDS (2x b128 per chunk) ----
    #pragma unroll
    for (int i = 0; i < NITER; ++i) {
        if (ad[i] >= 0) {
            v4f w0 = {va[i].x, vb[i].x, va[i].y, vb[i].y};
            v4f w1 = {va[i].z, vb[i].z, va[i].w, vb[i].w};
            *reinterpret_cast<v4f*>(&sbuf[ad[i]])     = w0;
            *reinterpret_cast<v4f*>(&sbuf[ad[i] + 4]) = w1;
        }
    }
    __syncthreads();

    // ---- Compute 4 samples/thread from LDS ----
    const int rx0 = X0 - 4, ry0 = Y0 - 3, rz0 = Z0 - 3;
    float a0[4], a1[4];
    #pragma unroll
    for (int j = 0; j < 4; ++j) {
        float dx = dxv[j], dy = dyv[j], dz = dzv[j];
        bool inH = (dx >= -4.0f) & (dx < 4.0f) &
                   (dy >= -3.0f) & (dy < 4.0f) &
                   (dz >= -3.0f) & (dz < 4.0f);
        if (inH) {
            // Region-local coordinates (always in-bounds under inH).
            float lx = (float)(xi + j + 4) + dx;
            float ly = (float)(yl + 3) + dy;
            float lz = (float)(zl + 3) + dz;
            float xf = floorf(lx), yf = floorf(ly), zf = floorf(lz);
            float fx = lx - xf, fy = ly - yf, fz = lz - zf;
            int ix = (int)xf, iy = (int)yf, iz = (int)zf;

            // Zero-weight masks vs volume bounds (values come edge-replicated
            // from LDS — no index clamping needed, staged data already clamped).
            int vx0 = ix + rx0, vy0 = iy + ry0, vz0 = iz + rz0;
            float wx0 = (vx0 >= 0  && vx0 < WW)     ? (1.0f - fx) : 0.0f;
            float wx1 = (vx0 >= -1 && vx0 < WW - 1) ? fx          : 0.0f;
            float wy0 = (vy0 >= 0  && vy0 < HH)     ? (1.0f - fy) : 0.0f;
            float wy1 = (vy0 >= -1 && vy0 < HH - 1) ? fy          : 0.0f;
            float wz0 = (vz0 >= 0  && vz0 < DD)     ? (1.0f - fz) : 0.0f;
            float wz1 = (vz0 >= -1 && vz0 < DD - 1) ? fz          : 0.0f;

            const float* pB = sbuf + 2 * ((iz * RYH + iy) * RXW + ix);
            // Each corner: both channels + both x in two adjacent 8B reads
            // (-> ds_read2_b64).
            v2f A00 = *(const v2f*)(pB);
            v2f B00 = *(const v2f*)(pB + 2);
            v2f A01 = *(const v2f*)(pB + 2 * RXW);
            v2f B01 = *(const v2f*)(pB + 2 * RXW + 2);
            const float* pC = pB + 2 * RYH * RXW;
            v2f A10 = *(const v2f*)(pC);
            v2f B10 = *(const v2f*)(pC + 2);
            v2f A11 = *(const v2f*)(pC + 2 * RXW);
            v2f B11 = *(const v2f*)(pC + 2 * RXW + 2);

            v2f c00 = s2(wx0) * A00 + s2(wx1) * B00;
            v2f c01 = s2(wx0) * A01 + s2(wx1) * B01;
            v2f c10 = s2(wx0) * A10 + s2(wx1) * B10;
            v2f c11 = s2(wx0) * A11 + s2(wx1) * B11;
            v2f m0  = s2(wy0) * c00 + s2(wy1) * c01;
            v2f m1  = s2(wy0) * c10 + s2(wy1) * c11;
            v2f r   = s2(wz0) * m0  + s2(wz1) * m1;
            a0[j] = r.x; a1[j] = r.y;
        } else {
            // ~0.3% of samples: outside staged halo (or NaN).
            sample_global(sb, sb + SP, x + j, y, z, dx, dy, dz, a0[j], a1[j]);
        }
    }

    int oo = b * NC * SP + (z * HH + y) * WW + x;
    v4f o0 = {a0[0], a0[1], a0[2], a0[3]};
    v4f o1 = {a1[0], a1[1], a1[2], a1[3]};
    st4_nt(out + oo, o0);
    st4_nt(out + oo + SP, o1);
}

extern "C" void kernel_launch(void* const* d_in, const int* in_sizes, int n_in,
                              void* d_out, int out_size, void* d_ws, size_t ws_size,
                              hipStream_t stream) {
    const float* src  = (const float*)d_in[0];
    const float* flow = (const float*)d_in[1];
    float* out = (float*)d_out;

    st_warp_kernel<<<NTILES, 512, 0, stream>>>(src, flow, out);
}